// Round 15
// baseline (69.883 us; speedup 1.0000x reference)
//
#include <hip/hip_runtime.h>

// MFMA fragment layouts (gfx950, 16x16 family, verified m89):
//   A-frag (M16,K32): lane l holds A[row=l&15][k=(l>>4)*8+e], e=0..7
//   B-frag (K32,N16): lane l holds B[k=(l>>4)*8+e][col=l&15]
//   C/D:              col=l&15, row=(l>>4)*4+reg
// h subtiled: hS[jt][et][16][16] f16 (512 B subtiles).
// ds_read_b64_tr_b16 (verified v6/v8): lane addr = subtile + lg*128 + ll*8;
// elem e = subtile[lg*4+e][ll] — the K16 PV A-frag.
//
// v15 pipeline (post-v14 lesson: counted lgkmcnt over mixed b128/tr DS ops is
// NOT reliable — only full drains): per tile ONE lgkmcnt(0), covered by
// construction: scores(t+1) issued at top of tile t (cover = full section),
// tr(t) issued right after tile t's score MFMAs (cover = select+softmax).
// Double-buffered score regs, single tr buffer. No counted waits.
// Geometry (v12/v13): 768-thr / 12-wave blocks, grid 256, 1 block/batch,
// waves 0..6 own strips {w, w+12}, waves 7..11 own {w}. LDS 69 KB.

typedef _Float16 half8 __attribute__((ext_vector_type(8)));
typedef _Float16 half4 __attribute__((ext_vector_type(4)));
typedef float f32x4 __attribute__((ext_vector_type(4)));

constexpr int B_ = 256, N_ = 300, E_ = 100;
constexpr float NEGINF = -9e15f;
constexpr float PADV   = -3e38f;
constexpr float LOG2E  = 1.44269504088896f;

constexpr int LDS_BYTES = 68096 + 1024;

#define DSB128(dst, addr, off) \
  asm volatile("ds_read_b128 %0, %1 offset:" #off : "=v"(dst) : "v"(addr))
#define DSB64(dst, addr, off) \
  asm volatile("ds_read_b64 %0, %1 offset:" #off : "=v"(dst) : "v"(addr))
#define TRD(dst, addr, off) \
  asm volatile("ds_read_b64_tr_b16 %0, %1 offset:" #off : "=v"(dst) : "v"(addr))
#define LGKM0 do { asm volatile("s_waitcnt lgkmcnt(0)" ::: "memory"); \
                   __builtin_amdgcn_sched_barrier(0); } while (0)

#define SCORE16(AJ0, AJ1, AJ2, AJT)                                            \
  c0 = __builtin_amdgcn_mfma_f32_16x16x32_f16(AJ0, g[0][0], c0, 0, 0, 0);      \
  c1 = __builtin_amdgcn_mfma_f32_16x16x32_f16(AJ0, g[0][1], c1, 0, 0, 0);      \
  c2 = __builtin_amdgcn_mfma_f32_16x16x32_f16(AJ0, g[0][2], c2, 0, 0, 0);      \
  c3 = __builtin_amdgcn_mfma_f32_16x16x32_f16(AJ0, g[0][3], c3, 0, 0, 0);      \
  c0 = __builtin_amdgcn_mfma_f32_16x16x32_f16(AJ1, g[1][0], c0, 0, 0, 0);      \
  c1 = __builtin_amdgcn_mfma_f32_16x16x32_f16(AJ1, g[1][1], c1, 0, 0, 0);      \
  c2 = __builtin_amdgcn_mfma_f32_16x16x32_f16(AJ1, g[1][2], c2, 0, 0, 0);      \
  c3 = __builtin_amdgcn_mfma_f32_16x16x32_f16(AJ1, g[1][3], c3, 0, 0, 0);      \
  c0 = __builtin_amdgcn_mfma_f32_16x16x32_f16(AJ2, g[2][0], c0, 0, 0, 0);      \
  c1 = __builtin_amdgcn_mfma_f32_16x16x32_f16(AJ2, g[2][1], c1, 0, 0, 0);      \
  c2 = __builtin_amdgcn_mfma_f32_16x16x32_f16(AJ2, g[2][2], c2, 0, 0, 0);      \
  c3 = __builtin_amdgcn_mfma_f32_16x16x32_f16(AJ2, g[2][3], c3, 0, 0, 0);      \
  c0 = __builtin_amdgcn_mfma_f32_16x16x16f16(AJT, gt[0], c0, 0, 0, 0);         \
  c1 = __builtin_amdgcn_mfma_f32_16x16x16f16(AJT, gt[1], c1, 0, 0, 0);         \
  c2 = __builtin_amdgcn_mfma_f32_16x16x16f16(AJT, gt[2], c2, 0, 0, 0);         \
  c3 = __builtin_amdgcn_mfma_f32_16x16x16f16(AJT, gt[3], c3, 0, 0, 0)

// One pipelined tile section. Issues next tile's score reads (other buffer)
// at top, computes this tile, issues this tile's tr reads after the score
// MFMAs, drains once before PV.
#define TILE_SECTION(AJ0, AJ1, AJ2, AJT, NX0, NX1, NX2, NXT,                   \
                     SO0, SO1, SO2, SOT, TO0, TO1, TO2, TO3, TO4, TO5, TO6,    \
                     NJC)                                                      \
  {                                                                            \
    DSB128(NX0, aA, SO0); DSB128(NX1, aA, SO1); DSB128(NX2, aA, SO2);          \
    DSB64(NXT, aT, SOT);                                                       \
    int jcn_ = (NJC); if (jcn_ > N_ - 4) jcn_ = N_ - 4;                        \
    const int4 avn_ = *(const int4*)(ajrow + jcn_);                            \
    f32x4 c0 = {0.f, 0.f, 0.f, 0.f}, c1 = c0, c2 = c0, c3 = c0;                \
    SCORE16(AJ0, AJ1, AJ2, AJT);                                               \
    TRD(tr[0], aR, TO0); TRD(tr[1], aR, TO1); TRD(tr[2], aR, TO2);             \
    TRD(tr[3], aR, TO3); TRD(tr[4], aR, TO4); TRD(tr[5], aR, TO5);             \
    TRD(tr[6], aR, TO6);                                                       \
    const int va[4] = {av.x, av.y, av.z, av.w};                                \
    float sv[4];                                                               \
    _Pragma("unroll")                                                          \
    for (int r = 0; r < 4; ++r) {                                              \
      const float e = (va[r] == 1) ? c0[r] : (va[r] == 2) ? c1[r]              \
                     : (va[r] == 3) ? c2[r] : c3[r];                           \
      sv[r] = (va[r] == 0) ? NEGINF : fmaxf(e, 0.2f * e);                      \
    }                                                                          \
    const float lmax = fmaxf(fmaxf(sv[0], sv[1]), fmaxf(sv[2], sv[3]));        \
    if (__any(lmax > m + 8.f)) {                                               \
      float tmax = fmaxf(lmax, __shfl_xor(lmax, 16));                          \
      tmax = fmaxf(tmax, __shfl_xor(tmax, 32));                                \
      const float nm = fmaxf(m, tmax);                                         \
      const float f = exp2f(m - nm);                                           \
      m = nm; lsum *= f;                                                       \
      _Pragma("unroll")                                                        \
      for (int t = 0; t < 7; ++t) {                                            \
        acc[t][0] *= f; acc[t][1] *= f; acc[t][2] *= f; acc[t][3] *= f;        \
      }                                                                        \
    }                                                                          \
    const float p0_ = exp2f(sv[0] - m), p1_ = exp2f(sv[1] - m);                \
    const float p2_ = exp2f(sv[2] - m), p3_ = exp2f(sv[3] - m);                \
    lsum += (p0_ + p1_) + (p2_ + p3_);                                         \
    half4 pb;                                                                  \
    pb[0] = (_Float16)p0_; pb[1] = (_Float16)p1_;                              \
    pb[2] = (_Float16)p2_; pb[3] = (_Float16)p3_;                              \
    LGKM0;                                                                     \
    _Pragma("unroll")                                                          \
    for (int t = 0; t < 7; ++t)                                                \
      acc[t] = __builtin_amdgcn_mfma_f32_16x16x16f16(tr[t], pb, acc[t], 0, 0, 0); \
    av = avn_;                                                                 \
  }

__global__ __launch_bounds__(768)
void gat_flash13(const float* __restrict__ H, const int* __restrict__ ADJ,
                 const float* __restrict__ A, float* __restrict__ OUT) {
  extern __shared__ char smraw[];
  _Float16* hS  = (_Float16*)smraw;
  _Float16* A16 = (_Float16*)(smraw + 68096);

  const int b = blockIdx.x;
  const int tid = threadIdx.x;
  const int w = tid >> 6, lane = tid & 63;
  const int lg = lane >> 4, ll = lane & 15;

  const float* Hb  = H + (size_t)b * (N_ * E_);
  const int*   AJb = ADJ + (size_t)b * (N_ * N_);

  // ---------------- stage h into subtiled LDS (zero-padded) ----------------
  for (int u = tid; u < 304 * 14; u += 768) {
    const int j = u / 14, hr = u % 14;
    half8 v;
#pragma unroll
    for (int e = 0; e < 8; ++e) {
      const int d = hr * 8 + e;
      v[e] = (_Float16)((j < N_ && d < E_) ? Hb[j * E_ + d] : 0.f);
    }
    *(half8*)&hS[(((j >> 4) * 7 + (hr >> 1)) << 8) + ((j & 15) << 4) + ((hr & 1) << 3)] = v;
  }
  if (tid < 64) {
    const int k = tid >> 4, oct = tid & 15;
    half8 v;
#pragma unroll
    for (int e = 0; e < 8; ++e) {
      const int d = oct * 8 + e;
      v[e] = (_Float16)((d < E_) ? A[k * E_ + d] * LOG2E : 0.f);   // log2-domain
    }
    *(half8*)&A16[k * 128 + oct * 8] = v;
  }
  __syncthreads();   // only barrier

  const unsigned ldsbase = (unsigned)(size_t)(void*)hS;

  // ========== strip loop: waves 0..6 own {w, w+12}; waves 7..11 own {w} ====
  for (int s = w; s < 19; s += 12) {
    const int irow = s * 16 + ll;
    const int irc  = irow < N_ ? irow : N_ - 1;

    // ---- G = h_i (.) A_k octets (B-operand fragments) ----
    half8 g[3][4];
    half4 gt[4];
#pragma unroll
    for (int db = 0; db < 3; ++db) {
      const int doct = db * 4 + lg;
      const half8 hi = *(const half8*)&hS[((s * 7 + (doct >> 1)) << 8) + (ll << 4) + ((doct & 1) << 3)];
#pragma unroll
      for (int k = 0; k < 4; ++k)
        g[db][k] = hi * *(const half8*)&A16[k * 128 + doct * 8];
    }
    {
      const half4 hit = *(const half4*)&hS[((s * 7 + 6) << 8) + (ll << 4) + lg * 4];
#pragma unroll
      for (int k = 0; k < 4; ++k)
        gt[k] = hit * *(const half4*)&A16[k * 128 + 96 + lg * 4];
    }

    float m = PADV, lsum = 0.f;
    f32x4 acc[7];
#pragma unroll
    for (int t = 0; t < 7; ++t) acc[t] = (f32x4){0.f, 0.f, 0.f, 0.f};

    const int* ajrow = AJb + (size_t)irc * N_;
    int4 av = *(const int4*)(ajrow + lg * 4);   // tile 0

    unsigned aA = ldsbase + ((unsigned)(lg >> 1) << 9) + ((unsigned)ll << 5) + ((unsigned)(lg & 1) << 4);
    unsigned aT = ldsbase + ((unsigned)ll << 5) + ((unsigned)lg << 3);
    unsigned aR = ldsbase + ((unsigned)ll << 3) + ((unsigned)lg << 7);

    half8 A0, A1, A2; half4 At;     // score buffer A
    half8 B0, B1, B2; half4 Bt;     // score buffer B
    half4 tr[7];                    // tr buffer (single)

    // prologue: issue tile-0 score reads, drain once (uncovered, tiny)
    DSB128(A0, aA, 0); DSB128(A1, aA, 1024); DSB128(A2, aA, 2048);
    DSB64(At, aT, 3072);
    LGKM0;

    for (int p = 0; p < 9; ++p) {
      // tile 2p  (bufA current; issue scores 2p+1 -> bufB at +3584)
      TILE_SECTION(A0, A1, A2, At, B0, B1, B2, Bt,
                   3584, 4608, 5632, 6656,
                   0, 512, 1024, 1536, 2048, 2560, 3072,
                   p * 32 + 16 + lg * 4);
      // tile 2p+1 (bufB current; issue scores 2p+2 -> bufA at +7168)
      TILE_SECTION(B0, B1, B2, Bt, A0, A1, A2, At,
                   7168, 8192, 9216, 10240,
                   3584, 4096, 4608, 5120, 5632, 6144, 6656,
                   p * 32 + 32 + lg * 4);
      aA += 7168; aT += 7168; aR += 7168;
    }

    // ================= tail tile 18 (scores already in bufA, drained) ======
    {
      f32x4 c0 = {0.f, 0.f, 0.f, 0.f}, c1 = c0, c2 = c0, c3 = c0;
      SCORE16(A0, A1, A2, At);
      TRD(tr[0], aR, 0);    TRD(tr[1], aR, 512);  TRD(tr[2], aR, 1024);
      TRD(tr[3], aR, 1536); TRD(tr[4], aR, 2048); TRD(tr[5], aR, 2560);
      TRD(tr[6], aR, 3072);
      const int va[4] = {av.x, av.y, av.z, av.w};
      float sv[4];
#pragma unroll
      for (int r = 0; r < 4; ++r) {
        const float e = (va[r] == 1) ? c0[r] : (va[r] == 2) ? c1[r]
                       : (va[r] == 3) ? c2[r] : c3[r];
        sv[r] = (va[r] == 0) ? NEGINF : fmaxf(e, 0.2f * e);
      }
      if (lg == 3) { sv[0] = PADV; sv[1] = PADV; sv[2] = PADV; sv[3] = PADV; }
      const float lmax = fmaxf(fmaxf(sv[0], sv[1]), fmaxf(sv[2], sv[3]));
      if (__any(lmax > m + 8.f)) {
        float tmax = fmaxf(lmax, __shfl_xor(lmax, 16));
        tmax = fmaxf(tmax, __shfl_xor(tmax, 32));
        const float nm = fmaxf(m, tmax);
        const float f = exp2f(m - nm);
        m = nm; lsum *= f;
#pragma unroll
        for (int t = 0; t < 7; ++t) {
          acc[t][0] *= f; acc[t][1] *= f; acc[t][2] *= f; acc[t][3] *= f;
        }
      }
      const float p0 = exp2f(sv[0] - m), p1 = exp2f(sv[1] - m);
      const float p2 = exp2f(sv[2] - m), p3 = exp2f(sv[3] - m);
      lsum += (p0 + p1) + (p2 + p3);
      half4 pb;
      pb[0] = (_Float16)p0; pb[1] = (_Float16)p1;
      pb[2] = (_Float16)p2; pb[3] = (_Float16)p3;
      LGKM0;
#pragma unroll
      for (int t = 0; t < 7; ++t)
        acc[t] = __builtin_amdgcn_mfma_f32_16x16x16f16(tr[t], pb, acc[t], 0, 0, 0);
    }

    // ---- epilogue: normalize + store ----
    lsum += __shfl_xor(lsum, 16);
    lsum += __shfl_xor(lsum, 32);
    const float rv = 1.f / lsum;
    if (irow < N_) {
      float* orow = OUT + ((size_t)b * N_ + irow) * E_;
#pragma unroll
      for (int t = 0; t < 7; ++t) {
        const int e0 = t * 16 + lg * 4;
        if (e0 < E_) {
          f32x4 o = acc[t];
          o[0] *= rv; o[1] *= rv; o[2] *= rv; o[3] *= rv;
          *(f32x4*)&orow[e0] = o;
        }
      }
    }
  }
}

extern "C" void kernel_launch(void* const* d_in, const int* in_sizes, int n_in,
                              void* d_out, int out_size, void* d_ws, size_t ws_size,
                              hipStream_t stream) {
  const float* H  = (const float*)d_in[0];
  const int*   AJ = (const int*)d_in[1];
  const float* A  = (const float*)d_in[2];
  float* OUT = (float*)d_out;

  (void)hipFuncSetAttribute(reinterpret_cast<const void*>(gat_flash13),
                            hipFuncAttributeMaxDynamicSharedMemorySize,
                            LDS_BYTES);
  gat_flash13<<<B_, 768, LDS_BYTES, stream>>>(H, AJ, A, OUT);
}